// Round 3
// baseline (707.768 us; speedup 1.0000x reference)
//
#include <hip/hip_runtime.h>
#include <math.h>

#define NN 10000
#define EE 320000
#define FIN 128
#define FHID 64
#define FOUT 32

typedef float f32x4 __attribute__((ext_vector_type(4)));

// ---------------- graph preprocessing ----------------

__global__ void k_count(const int* __restrict__ dst, int* __restrict__ deg, int E) {
    int e = blockIdx.x * blockDim.x + threadIdx.x;
    if (e < E) atomicAdd(&deg[dst[e]], 1);
}

// single-block exclusive scan of deg[n] -> rowptr[n+1]; also computes dinv
__global__ void k_scan(const int* __restrict__ cnt, int* __restrict__ rowptr,
                       float* __restrict__ dinv, int n) {
    __shared__ int buf[256];
    __shared__ int carry_s;
    if (threadIdx.x == 0) carry_s = 0;
    __syncthreads();
    int nC = (n + 255) / 256;
    for (int c = 0; c < nC; ++c) {
        int i = c * 256 + threadIdx.x;
        int v = (i < n) ? cnt[i] : 0;
        if (i < n) dinv[i] = rsqrtf((float)v + 1.0f);   // +1 self-loop
        buf[threadIdx.x] = v;
        __syncthreads();
        for (int off = 1; off < 256; off <<= 1) {
            int o = (threadIdx.x >= off) ? buf[threadIdx.x - off] : 0;
            __syncthreads();
            buf[threadIdx.x] += o;
            __syncthreads();
        }
        int incl = buf[threadIdx.x];
        int carry = carry_s;
        if (i < n) rowptr[i] = carry + incl - v;   // exclusive prefix
        __syncthreads();
        if (threadIdx.x == 255) carry_s = carry + incl;
        __syncthreads();
    }
    if (threadIdx.x == 0) rowptr[n] = carry_s;
}

__global__ void k_fill(const int* __restrict__ src, const int* __restrict__ dst,
                       const float* __restrict__ dinv, const int* __restrict__ rowptr,
                       int* __restrict__ fillcnt, int2* __restrict__ csr, int E) {
    int e = blockIdx.x * blockDim.x + threadIdx.x;
    if (e >= E) return;
    int s = src[e], d = dst[e];
    float w = dinv[s] * dinv[d];
    int pos = rowptr[d] + atomicAdd(&fillcnt[d], 1);
    csr[pos] = make_int2(s, __float_as_int(w));
}

// ---------------- dense transform: out[n][64] = in[n][K] @ W[K][64] ----------------
// CAT=1: W is concat(Wmu[64x32], Wls[64x32]) staged on the fly.

template<int K, int CAT>
__global__ __launch_bounds__(256) void k_xform(const float* __restrict__ in,
                                               const float* __restrict__ Wa,
                                               const float* __restrict__ Wb,
                                               float* __restrict__ out, int n) {
    __shared__ float Ws[K * 64];
    if (CAT) {
        for (int i = threadIdx.x; i < 64 * 64; i += 256) {
            int k = i >> 6, j = i & 63;
            Ws[i] = (j < 32) ? Wa[k * 32 + j] : Wb[k * 32 + (j - 32)];
        }
    } else {
        for (int i = threadIdx.x; i < K * 64; i += 256) Ws[i] = Wa[i];
    }
    __syncthreads();
    int lane = threadIdx.x & 63;
    int wv = threadIdx.x >> 6;
#pragma unroll
    for (int r = 0; r < 4; ++r) {
        int row = blockIdx.x * 16 + wv * 4 + r;   // wave-uniform predicate
        if (row >= n) continue;
        const float* xr = in + (long long)row * K;
        float xa = xr[lane];
        float xb = (K > 64) ? xr[(K > 64 ? 64 : 0) + lane] : 0.0f;
        float acc = 0.0f;
#pragma unroll
        for (int k = 0; k < K; ++k) {
            float xk = (k < 64) ? __shfl(xa, k) : __shfl(xb, k - 64);
            acc += xk * Ws[k * 64 + lane];
        }
        out[(long long)row * 64 + lane] = acc;
    }
}

// ---------------- propagate: one wave per node, lane = feature ----------------
// MODE 0: out[i][f] = relu(agg + b0[f])           (out is [n][64])
// MODE 1: v = agg + cat(bmu,bls)[f]; z = mu + eps*exp(min(ls,10))  (out is z [n][32])

template<int MODE>
__global__ __launch_bounds__(256) void k_prop(const float* __restrict__ t,
                                              const int2* __restrict__ csr,
                                              const int* __restrict__ rowptr,
                                              const float* __restrict__ dinv,
                                              const float* __restrict__ ba,
                                              const float* __restrict__ bb,
                                              const float* __restrict__ eps,
                                              float* __restrict__ out, int n) {
    int lane = threadIdx.x & 63;
    int node = blockIdx.x * (blockDim.x >> 6) + (threadIdx.x >> 6);
    if (node >= n) return;
    float di = dinv[node];
    float acc = di * di * t[(long long)node * 64 + lane];   // self-loop
    int e = rowptr[node], end = rowptr[node + 1];
    for (; e < end; ++e) {
        int2 ed = csr[e];
        acc += __int_as_float(ed.y) * t[(long long)ed.x * 64 + lane];
    }
    if (MODE == 0) {
        out[(long long)node * 64 + lane] = fmaxf(acc + ba[lane], 0.0f);
    } else {
        float v = acc + ((lane < 32) ? ba[lane] : bb[lane - 32]);
        float ls = __shfl(v, lane | 32);
        if (lane < 32) {
            float zv = v + eps[(long long)node * 32 + lane] * __expf(fminf(ls, 10.0f));
            out[(long long)node * 32 + lane] = zv;
        }
    }
}

// ---------------- decoder: out = sigmoid(z @ z^T), 128x128 tiles ----------------

__global__ __launch_bounds__(256) void k_decoder(const float* __restrict__ z,
                                                 float* __restrict__ out, int n) {
    __shared__ float ziT[32][132];   // k-major, padded
    __shared__ float zjT[32][132];
    int i0 = blockIdx.y * 128;
    int j0 = blockIdx.x * 128;
    int t = threadIdx.x;
#pragma unroll
    for (int r = 0; r < 4; ++r) {
        int idx = t + r * 256;          // 0..1023
        int row = idx >> 3;             // 0..127
        int c4 = (idx & 7) << 2;        // 0,4,...,28
        float4 vi = make_float4(0.f, 0.f, 0.f, 0.f);
        float4 vj = make_float4(0.f, 0.f, 0.f, 0.f);
        if (i0 + row < n) vi = *(const float4*)&z[(long long)(i0 + row) * 32 + c4];
        if (j0 + row < n) vj = *(const float4*)&z[(long long)(j0 + row) * 32 + c4];
        ziT[c4 + 0][row] = vi.x; ziT[c4 + 1][row] = vi.y;
        ziT[c4 + 2][row] = vi.z; ziT[c4 + 3][row] = vi.w;
        zjT[c4 + 0][row] = vj.x; zjT[c4 + 1][row] = vj.y;
        zjT[c4 + 2][row] = vj.z; zjT[c4 + 3][row] = vj.w;
    }
    __syncthreads();

    int tr = t >> 4, tc = t & 15;
    int rbase = tr * 8, cbase = tc * 8;
    float acc[8][8];
#pragma unroll
    for (int u = 0; u < 8; ++u)
#pragma unroll
        for (int v = 0; v < 8; ++v) acc[u][v] = 0.0f;

#pragma unroll 4
    for (int k = 0; k < 32; ++k) {
        float4 a0 = *(const float4*)&ziT[k][rbase];
        float4 a1 = *(const float4*)&ziT[k][rbase + 4];
        float4 b0v = *(const float4*)&zjT[k][cbase];
        float4 b1v = *(const float4*)&zjT[k][cbase + 4];
        float a[8] = {a0.x, a0.y, a0.z, a0.w, a1.x, a1.y, a1.z, a1.w};
        float b[8] = {b0v.x, b0v.y, b0v.z, b0v.w, b1v.x, b1v.y, b1v.z, b1v.w};
#pragma unroll
        for (int u = 0; u < 8; ++u)
#pragma unroll
            for (int v = 0; v < 8; ++v)
                acc[u][v] += a[u] * b[v];
    }

#pragma unroll
    for (int u = 0; u < 8; ++u) {
        int gi = i0 + rbase + u;
        if (gi < n) {
            float r[8];
#pragma unroll
            for (int v = 0; v < 8; ++v)
                r[v] = __fdividef(1.0f, 1.0f + __expf(-acc[u][v]));
            long long base = (long long)gi * n + (j0 + cbase);
            if (j0 + cbase + 8 <= n) {
                f32x4 lo = {r[0], r[1], r[2], r[3]};
                f32x4 hi = {r[4], r[5], r[6], r[7]};
                __builtin_nontemporal_store(lo, (f32x4*)&out[base]);
                __builtin_nontemporal_store(hi, (f32x4*)&out[base + 4]);
            } else {
#pragma unroll
                for (int v = 0; v < 8; ++v)
                    if (j0 + cbase + v < n) out[base + v] = r[v];
            }
        }
    }
}

// ---------------- launch ----------------

extern "C" void kernel_launch(void* const* d_in, const int* in_sizes, int n_in,
                              void* d_out, int out_size, void* d_ws, size_t ws_size,
                              hipStream_t stream) {
    const float* x   = (const float*)d_in[0];
    const int*   ei  = (const int*)d_in[1];
    const float* eps = (const float*)d_in[2];
    const float* W0  = (const float*)d_in[3];
    const float* b0  = (const float*)d_in[4];
    const float* W1  = (const float*)d_in[5];
    const float* b1  = (const float*)d_in[6];
    const float* Wmu = (const float*)d_in[7];
    const float* bmu = (const float*)d_in[8];
    const float* Wls = (const float*)d_in[9];
    const float* bls = (const float*)d_in[10];
    float* out = (float*)d_out;

    int E = in_sizes[1] / 2;
    int n = in_sizes[0] / FIN;

    char* ws = (char*)d_ws;
    int*   deg    = (int*)(ws + 0);            // n ints (also reused as fill counter)
    float* dinv   = (float*)(ws + 40960);      // n floats
    int*   rowptr = (int*)(ws + 81920);        // n+1 ints
    int2*  csr    = (int2*)(ws + 122880);      // E int2
    float* bufA   = (float*)(ws + 2682880);    // n*64
    float* bufB   = (float*)(ws + 5242880);    // n*64
    float* z      = (float*)(ws + 7802880);    // n*32

    const int* src = ei;
    const int* dst = ei + E;

    (void)hipMemsetAsync(deg, 0, n * sizeof(int), stream);
    k_count<<<(E + 255) / 256, 256, 0, stream>>>(dst, deg, E);
    k_scan<<<1, 256, 0, stream>>>(deg, rowptr, dinv, n);
    (void)hipMemsetAsync(deg, 0, n * sizeof(int), stream);
    k_fill<<<(E + 255) / 256, 256, 0, stream>>>(src, dst, dinv, rowptr, deg, csr, E);

    int xblocks = (n + 15) / 16;
    int pblocks = (n + 3) / 4;
    k_xform<128, 0><<<xblocks, 256, 0, stream>>>(x, W0, nullptr, bufA, n);
    k_prop<0><<<pblocks, 256, 0, stream>>>(bufA, csr, rowptr, dinv, b0, nullptr, nullptr, bufB, n);
    k_xform<64, 0><<<xblocks, 256, 0, stream>>>(bufB, W1, nullptr, bufA, n);
    k_prop<0><<<pblocks, 256, 0, stream>>>(bufA, csr, rowptr, dinv, b1, nullptr, nullptr, bufB, n);
    k_xform<64, 1><<<xblocks, 256, 0, stream>>>(bufB, Wmu, Wls, bufA, n);
    k_prop<1><<<pblocks, 256, 0, stream>>>(bufA, csr, rowptr, dinv, bmu, bls, eps, z, n);

    int nt = (n + 127) / 128;
    dim3 g(nt, nt);
    k_decoder<<<g, 256, 0, stream>>>(z, out, n);
}

// Round 4
// 650.301 us; speedup vs baseline: 1.0884x; 1.0884x over previous
//
#include <hip/hip_runtime.h>
#include <math.h>

#define FIN 128

typedef float f32x4 __attribute__((ext_vector_type(4)));

// ---------------- graph preprocessing ----------------

__global__ void k_count(const int* __restrict__ dst, int* __restrict__ deg, int E) {
    int e = blockIdx.x * blockDim.x + threadIdx.x;
    if (e < E) atomicAdd(&deg[dst[e]], 1);
}

// 1 block: per-256-chunk sums, then wave-wide exclusive scan of chunk sums
__global__ __launch_bounds__(256) void k_prescan(const int* __restrict__ deg,
                                                 int* __restrict__ boff,
                                                 int* __restrict__ rowptr, int n) {
    __shared__ int bs[64];
    int NB = (n + 255) >> 8;       // <= 64 (n <= 16384)
    int c = threadIdx.x;
    if (c < 64) {
        int s = 0;
        if (c < NB) {
            int base = c << 8;
            int lim = n - base; if (lim > 256) lim = 256;
            for (int i = 0; i < lim; ++i) s += deg[base + i];
        }
        bs[c] = s;
    }
    __syncthreads();
    if (threadIdx.x < 64) {                       // one wave
        int v = bs[threadIdx.x];
        int incl = v;
        for (int off = 1; off < 64; off <<= 1) {
            int o = __shfl_up(incl, off);
            if ((int)threadIdx.x >= off) incl += o;
        }
        if ((int)threadIdx.x < NB) boff[threadIdx.x] = incl - v;   // exclusive
        if (threadIdx.x == 63) rowptr[n] = incl;                   // total = E
    }
}

__global__ __launch_bounds__(256) void k_scatter(const int* __restrict__ deg,
                                                 const int* __restrict__ boff,
                                                 int* __restrict__ rowptr,
                                                 float* __restrict__ dinv, int n) {
    __shared__ int buf[256];
    int i = blockIdx.x * 256 + threadIdx.x;
    int v = (i < n) ? deg[i] : 0;
    if (i < n) dinv[i] = rsqrtf((float)v + 1.0f);   // +1 self-loop
    buf[threadIdx.x] = v;
    __syncthreads();
    for (int off = 1; off < 256; off <<= 1) {
        int o = (threadIdx.x >= off) ? buf[threadIdx.x - off] : 0;
        __syncthreads();
        buf[threadIdx.x] += o;
        __syncthreads();
    }
    if (i < n) rowptr[i] = boff[blockIdx.x] + buf[threadIdx.x] - v;  // exclusive
}

__global__ void k_fill(const int* __restrict__ src, const int* __restrict__ dst,
                       const float* __restrict__ dinv, const int* __restrict__ rowptr,
                       int* __restrict__ fillcnt, int2* __restrict__ csr, int E) {
    int e = blockIdx.x * blockDim.x + threadIdx.x;
    if (e >= E) return;
    int s = src[e], d = dst[e];
    float w = dinv[s] * dinv[d];
    int pos = rowptr[d] + atomicAdd(&fillcnt[d], 1);
    csr[pos] = make_int2(s, __float_as_int(w));
}

// ---------------- dense transform: out[n][64] = in[n][K] @ W[K][64] ----------------

template<int K, int CAT>
__global__ __launch_bounds__(256) void k_xform(const float* __restrict__ in,
                                               const float* __restrict__ Wa,
                                               const float* __restrict__ Wb,
                                               float* __restrict__ out, int n) {
    __shared__ float Ws[K * 64];
    if (CAT) {
        for (int i = threadIdx.x; i < 64 * 64; i += 256) {
            int k = i >> 6, j = i & 63;
            Ws[i] = (j < 32) ? Wa[k * 32 + j] : Wb[k * 32 + (j - 32)];
        }
    } else {
        for (int i = threadIdx.x; i < K * 64; i += 256) Ws[i] = Wa[i];
    }
    __syncthreads();
    int lane = threadIdx.x & 63;
    int wv = threadIdx.x >> 6;
#pragma unroll
    for (int r = 0; r < 4; ++r) {
        int row = blockIdx.x * 16 + wv * 4 + r;
        if (row >= n) continue;
        const float* xr = in + (long long)row * K;
        float xa = xr[lane];
        float xb = (K > 64) ? xr[(K > 64 ? 64 : 0) + lane] : 0.0f;
        float acc = 0.0f;
#pragma unroll
        for (int k = 0; k < K; ++k) {
            float xk = (k < 64) ? __shfl(xa, k) : __shfl(xb, k - 64);
            acc += xk * Ws[k * 64 + lane];
        }
        out[(long long)row * 64 + lane] = acc;
    }
}

// ---------------- propagate: one wave per node, edges batched via shfl ----------------

template<int MODE>
__global__ __launch_bounds__(256) void k_prop(const float* __restrict__ t,
                                              const int2* __restrict__ csr,
                                              const int* __restrict__ rowptr,
                                              const float* __restrict__ dinv,
                                              const float* __restrict__ ba,
                                              const float* __restrict__ bb,
                                              const float* __restrict__ eps,
                                              float* __restrict__ out, int n) {
    int lane = threadIdx.x & 63;
    int node = blockIdx.x * 4 + (threadIdx.x >> 6);
    if (node >= n) return;
    float di = dinv[node];
    float acc = di * di * t[(long long)node * 64 + lane];   // self-loop
    int e0 = rowptr[node], e1 = rowptr[node + 1];
    for (int base = e0; base < e1; base += 64) {
        int m = e1 - base; if (m > 64) m = 64;
        int2 my = make_int2(0, 0);
        if (lane < m) my = csr[base + lane];
        for (int i = 0; i < m; ++i) {
            int s = __shfl(my.x, i);
            float w = __int_as_float(__shfl(my.y, i));
            acc += w * t[(long long)s * 64 + lane];
        }
    }
    if (MODE == 0) {
        out[(long long)node * 64 + lane] = fmaxf(acc + ba[lane], 0.0f);
    } else {
        float v = acc + ((lane < 32) ? ba[lane] : bb[lane - 32]);
        float ls = __shfl(v, lane | 32);
        if (lane < 32) {
            float zv = v + eps[(long long)node * 32 + lane] * __expf(fminf(ls, 10.0f));
            out[(long long)node * 32 + lane] = zv;
        }
    }
}

// ---------------- decoder: out = sigmoid(z @ z^T), 128x128 tiles ----------------

__global__ __launch_bounds__(256) void k_decoder(const float* __restrict__ z,
                                                 float* __restrict__ out, int n) {
    __shared__ float ziT[32][132];
    __shared__ float zjT[32][132];
    int i0 = blockIdx.y * 128;
    int j0 = blockIdx.x * 128;
    int t = threadIdx.x;
#pragma unroll
    for (int r = 0; r < 4; ++r) {
        int idx = t + r * 256;
        int row = idx >> 3;
        int c4 = (idx & 7) << 2;
        float4 vi = make_float4(0.f, 0.f, 0.f, 0.f);
        float4 vj = make_float4(0.f, 0.f, 0.f, 0.f);
        if (i0 + row < n) vi = *(const float4*)&z[(long long)(i0 + row) * 32 + c4];
        if (j0 + row < n) vj = *(const float4*)&z[(long long)(j0 + row) * 32 + c4];
        ziT[c4 + 0][row] = vi.x; ziT[c4 + 1][row] = vi.y;
        ziT[c4 + 2][row] = vi.z; ziT[c4 + 3][row] = vi.w;
        zjT[c4 + 0][row] = vj.x; zjT[c4 + 1][row] = vj.y;
        zjT[c4 + 2][row] = vj.z; zjT[c4 + 3][row] = vj.w;
    }
    __syncthreads();

    int tr = t >> 4, tc = t & 15;
    int rbase = tr * 8, cbase = tc * 8;
    float acc[8][8];
#pragma unroll
    for (int u = 0; u < 8; ++u)
#pragma unroll
        for (int v = 0; v < 8; ++v) acc[u][v] = 0.0f;

#pragma unroll 4
    for (int k = 0; k < 32; ++k) {
        float4 a0 = *(const float4*)&ziT[k][rbase];
        float4 a1 = *(const float4*)&ziT[k][rbase + 4];
        float4 b0v = *(const float4*)&zjT[k][cbase];
        float4 b1v = *(const float4*)&zjT[k][cbase + 4];
        float a[8] = {a0.x, a0.y, a0.z, a0.w, a1.x, a1.y, a1.z, a1.w};
        float b[8] = {b0v.x, b0v.y, b0v.z, b0v.w, b1v.x, b1v.y, b1v.z, b1v.w};
#pragma unroll
        for (int u = 0; u < 8; ++u)
#pragma unroll
            for (int v = 0; v < 8; ++v)
                acc[u][v] += a[u] * b[v];
    }

#pragma unroll
    for (int u = 0; u < 8; ++u) {
        int gi = i0 + rbase + u;
        if (gi < n) {
            float r[8];
#pragma unroll
            for (int v = 0; v < 8; ++v)
                r[v] = __fdividef(1.0f, 1.0f + __expf(-acc[u][v]));
            long long base = (long long)gi * n + (j0 + cbase);
            if (j0 + cbase + 8 <= n) {
                *(float4*)&out[base]     = make_float4(r[0], r[1], r[2], r[3]);
                *(float4*)&out[base + 4] = make_float4(r[4], r[5], r[6], r[7]);
            } else {
#pragma unroll
                for (int v = 0; v < 8; ++v)
                    if (j0 + cbase + v < n) out[base + v] = r[v];
            }
        }
    }
}

// ---------------- launch ----------------

extern "C" void kernel_launch(void* const* d_in, const int* in_sizes, int n_in,
                              void* d_out, int out_size, void* d_ws, size_t ws_size,
                              hipStream_t stream) {
    const float* x   = (const float*)d_in[0];
    const int*   ei  = (const int*)d_in[1];
    const float* eps = (const float*)d_in[2];
    const float* W0  = (const float*)d_in[3];
    const float* b0  = (const float*)d_in[4];
    const float* W1  = (const float*)d_in[5];
    const float* b1  = (const float*)d_in[6];
    const float* Wmu = (const float*)d_in[7];
    const float* bmu = (const float*)d_in[8];
    const float* Wls = (const float*)d_in[9];
    const float* bls = (const float*)d_in[10];
    float* out = (float*)d_out;

    int E = in_sizes[1] / 2;
    int n = in_sizes[0] / FIN;

    char* ws = (char*)d_ws;
    int*   deg     = (int*)(ws + 0);            // n ints
    int*   fillcnt = (int*)(ws + 40960);        // n ints (zeroed with deg, one memset)
    int*   boff    = (int*)(ws + 81920);        // 64 ints
    int*   rowptr  = (int*)(ws + 82432);        // n+1 ints
    float* dinv    = (float*)(ws + 124928);     // n floats
    int2*  csr     = (int2*)(ws + 165888);      // E int2
    float* bufA    = (float*)(ws + 2725888);    // n*64
    float* bufB    = (float*)(ws + 5285888);    // n*64
    float* z       = (float*)(ws + 7845888);    // n*32

    const int* src = ei;
    const int* dst = ei + E;

    (void)hipMemsetAsync(deg, 0, 81920, stream);   // deg + fillcnt
    k_count<<<(E + 255) / 256, 256, 0, stream>>>(dst, deg, E);
    k_prescan<<<1, 256, 0, stream>>>(deg, boff, rowptr, n);
    int nb = (n + 255) / 256;
    k_scatter<<<nb, 256, 0, stream>>>(deg, boff, rowptr, dinv, n);
    k_fill<<<(E + 255) / 256, 256, 0, stream>>>(src, dst, dinv, rowptr, fillcnt, csr, E);

    int xblocks = (n + 15) / 16;
    int pblocks = (n + 3) / 4;
    k_xform<128, 0><<<xblocks, 256, 0, stream>>>(x, W0, nullptr, bufA, n);
    k_prop<0><<<pblocks, 256, 0, stream>>>(bufA, csr, rowptr, dinv, b0, nullptr, nullptr, bufB, n);
    k_xform<64, 0><<<xblocks, 256, 0, stream>>>(bufB, W1, nullptr, bufA, n);
    k_prop<0><<<pblocks, 256, 0, stream>>>(bufA, csr, rowptr, dinv, b1, nullptr, nullptr, bufB, n);
    k_xform<64, 1><<<xblocks, 256, 0, stream>>>(bufB, Wmu, Wls, bufA, n);
    k_prop<1><<<pblocks, 256, 0, stream>>>(bufA, csr, rowptr, dinv, bmu, bls, eps, z, n);

    int nt = (n + 127) / 128;
    dim3 g(nt, nt);
    k_decoder<<<g, 256, 0, stream>>>(z, out, n);
}